// Round 2
// baseline (504.087 us; speedup 1.0000x reference)
//
#include <hip/hip_runtime.h>
#include <hip/hip_bf16.h>
#include <cstdint>

typedef __hip_bfloat16 bf16;
typedef __attribute__((ext_vector_type(8))) short short8;
typedef __attribute__((ext_vector_type(4))) float f32x4;
typedef unsigned int u32;

#define BB 2
#define LL 2048
#define DM 1024
#define DI 2048
#define DS 128
#define NH 32
#define HD 64
#define CONVD 2304
#define DPROJ 4384
#define DPAD 4480
#define NBL (BB*LL)
#define NCHK 16
#define CLEN 128

__device__ __forceinline__ float bf2f(bf16 v) { return __bfloat162float(v); }
__device__ __forceinline__ bf16 f2bf(float f) { return __float2bfloat16(f); }

__device__ __forceinline__ void gload16(const void* g, void* l) {
  __builtin_amdgcn_global_load_lds(
      (const __attribute__((address_space(1))) u32*)g,
      (__attribute__((address_space(3))) u32*)l, 16, 0, 0);
}

// ---------------- f32 -> bf16 cast (vectorized) ----------------
__global__ __launch_bounds__(256)
void k_cast(const float* __restrict__ src, bf16* __restrict__ dst, int n4)
{
  int i = blockIdx.x * blockDim.x + threadIdx.x;
  const int stride = gridDim.x * blockDim.x;
  for (; i < n4; i += stride) {
    const float4 v = ((const float4*)src)[i];
    union { unsigned short u[4]; uint2 w; } o;
    bf16 t0 = f2bf(v.x), t1 = f2bf(v.y), t2 = f2bf(v.z), t3 = f2bf(v.w);
    o.u[0] = *(unsigned short*)&t0; o.u[1] = *(unsigned short*)&t1;
    o.u[2] = *(unsigned short*)&t2; o.u[3] = *(unsigned short*)&t3;
    *(uint2*)(dst + (size_t)i*4) = o.w;
  }
}

// ---------------- GEMM (NT): out[m][n] = sum_k A[m][k] * W[n][k] ----------------
// 128x128 tile, BK=64, 4 waves (2x2), 16x16x32 bf16 MFMA, global_load_lds staging.
// Output f32; optionally adds f32 residual.
template<bool ADDRES>
__global__ __launch_bounds__(256)
void k_gemm_nt(const bf16* __restrict__ A, const bf16* __restrict__ W,
               int K, int Nw, int ldo,
               float* __restrict__ outf, const float* __restrict__ resid)
{
  __shared__ __align__(16) unsigned short As[128*64];
  __shared__ __align__(16) unsigned short Ws[128*64];
  const int tid = threadIdx.x;
  const int w = tid >> 6, lane = tid & 63;
  const int m0 = blockIdx.x * 128, n0 = blockIdx.y * 128;
  const int wr = w >> 1, wc = w & 1;
  f32x4 acc[4][4] = {};
  const int r0 = lane & 15;
  const int kq = (lane >> 4) * 8;

  for (int k0 = 0; k0 < K; k0 += 64) {
    #pragma unroll
    for (int it = 0; it < 4; ++it) {
      const int seg = w*4 + it;               // 0..15 (1KB segments)
      const int idx = seg*512 + lane*8;       // bf16 element index in tile
      const int row = idx >> 6, col = idx & 63;
      const bf16* ga = A + (size_t)(m0 + row)*K + (k0 + col);
      gload16(ga, (char*)As + seg*1024);
      int rw = n0 + row; rw = (rw < Nw) ? rw : (Nw - 1);
      const bf16* gw = W + (size_t)rw*K + (k0 + col);
      gload16(gw, (char*)Ws + seg*1024);
    }
    __syncthreads();
    #pragma unroll
    for (int kk = 0; kk < 64; kk += 32) {
      short8 af[4], bw[4];
      #pragma unroll
      for (int mi = 0; mi < 4; ++mi)
        af[mi] = *(const short8*)(As + (wr*64 + mi*16 + r0)*64 + kk + kq);
      #pragma unroll
      for (int ni = 0; ni < 4; ++ni)
        bw[ni] = *(const short8*)(Ws + (wc*64 + ni*16 + r0)*64 + kk + kq);
      #pragma unroll
      for (int mi = 0; mi < 4; ++mi)
        #pragma unroll
        for (int ni = 0; ni < 4; ++ni)
          acc[mi][ni] = __builtin_amdgcn_mfma_f32_16x16x32_bf16(af[mi], bw[ni], acc[mi][ni], 0, 0, 0);
    }
    __syncthreads();
  }
  const int rr = (lane >> 4) * 4;
  #pragma unroll
  for (int mi = 0; mi < 4; ++mi) {
    #pragma unroll
    for (int ni = 0; ni < 4; ++ni) {
      const int col = n0 + wc*64 + ni*16 + r0;
      #pragma unroll
      for (int r = 0; r < 4; ++r) {
        const int row = m0 + wr*64 + mi*16 + rr + r;
        float v = acc[mi][ni][r];
        if (ADDRES) v += resid[(size_t)row*ldo + col];
        outf[(size_t)row*ldo + col] = v;
      }
    }
  }
}

// ---------------- conv1d + silu + dt/ldA prep ----------------
__global__ __launch_bounds__(256)
void k_conv(const float* __restrict__ zx, const float* __restrict__ convw,
            const float* __restrict__ convb, const float* __restrict__ dtb,
            const float* __restrict__ alog,
            float* __restrict__ xs, float* __restrict__ dt,
            float* __restrict__ ldA, float* __restrict__ Bc, float* __restrict__ Cc)
{
  const int bl = blockIdx.x;
  const int l = bl & (LL - 1);
  const int tid = threadIdx.x;
  if (tid < NH) {
    float raw = zx[(size_t)bl*DPAD + (DI + CONVD) + tid] + dtb[tid];
    float sp = (raw > 20.f) ? raw : log1pf(__expf(raw));
    float Ah = -__expf(alog[tid]);
    dt[(size_t)bl*NH + tid] = sp;
    ldA[(size_t)bl*NH + tid] = sp * Ah;
  }
  #pragma unroll
  for (int i = 0; i < 9; ++i) {
    const int c = tid + i*256;   // 2304 = 9*256
    float acc = convb[c];
    #pragma unroll
    for (int k = 0; k < 4; ++k) {
      const int tt = l - 3 + k;
      if (tt >= 0) acc += zx[(size_t)(bl - 3 + k)*DPAD + DI + c] * convw[c*4 + k];
    }
    const float v = acc / (1.f + __expf(-acc));
    if (c < DI)            xs[(size_t)bl*DI + c] = v;
    else if (c < DI + DS)  Bc[(size_t)bl*DS + (c - DI)] = v;
    else                   Cc[(size_t)bl*DS + (c - DI - DS)] = v;
  }
}

// ---------------- scan phase A: per-chunk local end-state ----------------
__global__ __launch_bounds__(256)
void k_chunk_state(const float* __restrict__ xs, const float* __restrict__ dt,
                   const float* __restrict__ ldA, const float* __restrict__ Bc,
                   float* __restrict__ Sloc, float* __restrict__ clog)
{
  const int bidx = blockIdx.x;
  const int c = bidx & (NCHK - 1);
  const int h = (bidx >> 4) & (NH - 1);
  const int b = bidx >> 9;
  const int t0 = c * CLEN;
  const int tid = threadIdx.x;
  __shared__ float la[CLEN];
  if (tid < CLEN) la[tid] = ldA[((size_t)(b*LL + t0 + tid))*NH + h];
  __syncthreads();
  for (int off = 1; off < CLEN; off <<= 1) {
    float v = 0.f;
    if (tid >= off && tid < CLEN) v = la[tid - off];
    __syncthreads();
    if (tid >= off && tid < CLEN) la[tid] += v;
    __syncthreads();
  }
  const float Ltot = la[CLEN - 1];
  if (tid == 0) clog[bidx] = Ltot;
  const int lane = tid & 63;
  const int gg = __builtin_amdgcn_readfirstlane(tid >> 6);
  float s[32];
  #pragma unroll
  for (int j = 0; j < 32; ++j) s[j] = 0.f;
  for (int t = 0; t < CLEN; ++t) {
    const size_t bl = (size_t)(b*LL + t0 + t);
    const float wv = __expf(Ltot - la[t]);            // decay t -> chunk end
    const float a = wv * dt[bl*NH + h] * xs[bl*DI + h*HD + lane];
    const float* Bt = Bc + bl*DS + gg*32;
    #pragma unroll
    for (int j = 0; j < 32; ++j) s[j] = fmaf(a, Bt[j], s[j]);
  }
  float* So = Sloc + (size_t)bidx*8192 + lane*128 + gg*32;
  #pragma unroll
  for (int j = 0; j < 32; ++j) So[j] = s[j];
}

// ---------------- scan phase B: inter-chunk recurrence (in-place: Sloc -> Sinit) ----------------
__global__ __launch_bounds__(256)
void k_chunk_combine(float* __restrict__ Sloc, const float* __restrict__ clog)
{
  const int bh = blockIdx.x >> 3;                    // 64 (b,h)
  const int e0 = ((blockIdx.x & 7) * 256 + threadIdx.x) * 4;
  float4 tmp = {0.f, 0.f, 0.f, 0.f};
  for (int c = 0; c < NCHK; ++c) {
    float* Sp = Sloc + ((size_t)(bh*NCHK + c))*8192 + e0;
    const float4 loc = *(const float4*)Sp;
    *(float4*)Sp = tmp;                              // now holds S_init[c]
    const float P = __expf(clog[bh*NCHK + c]);
    tmp.x = P*tmp.x + loc.x;
    tmp.y = P*tmp.y + loc.y;
    tmp.z = P*tmp.z + loc.z;
    tmp.w = P*tmp.w + loc.w;
  }
}

// ---------------- scan phase C: intra-chunk scan from S_init, emit y ----------------
__global__ __launch_bounds__(256)
void k_chunk_scan(const float* __restrict__ xs, const float* __restrict__ dt,
                  const float* __restrict__ ldA, const float* __restrict__ Bc,
                  const float* __restrict__ Cc, const float* __restrict__ Sinit,
                  const float* __restrict__ Dv, float* __restrict__ y)
{
  const int bidx = blockIdx.x;
  const int c = bidx & (NCHK - 1);
  const int h = (bidx >> 4) & (NH - 1);
  const int b = bidx >> 9;
  const int t0 = c * CLEN;
  const int tid = threadIdx.x;
  __shared__ float lr[CLEN];
  __shared__ float yl[16][4][64];
  if (tid < CLEN) lr[tid] = ldA[((size_t)(b*LL + t0 + tid))*NH + h];
  __syncthreads();
  const int lane = tid & 63;
  const int gg = __builtin_amdgcn_readfirstlane(tid >> 6);
  const float Dh = Dv[h];
  float s[32];
  const float* Si = Sinit + (size_t)bidx*8192 + lane*128 + gg*32;
  #pragma unroll
  for (int j = 0; j < 32; ++j) s[j] = Si[j];
  for (int tb = 0; tb < CLEN/16; ++tb) {
    for (int ti = 0; ti < 16; ++ti) {
      const int t = tb*16 + ti;
      const size_t bl = (size_t)(b*LL + t0 + t);
      const float dAt = __expf(lr[t]);
      const float xdtp = dt[bl*NH + h] * xs[bl*DI + h*HD + lane];
      const float* Bt = Bc + bl*DS + gg*32;
      const float* Ct = Cc + bl*DS + gg*32;
      float yp = 0.f;
      #pragma unroll
      for (int j = 0; j < 32; ++j) {
        s[j] = dAt*s[j] + xdtp*Bt[j];
        yp = fmaf(s[j], Ct[j], yp);
      }
      yl[ti][gg][lane] = yp;
    }
    __syncthreads();
    #pragma unroll
    for (int ii = 0; ii < 4; ++ii) {
      const int idx = tid + ii*256;
      const int ti = idx >> 6, p = idx & 63;
      const size_t bl = (size_t)(b*LL + t0 + tb*16 + ti);
      float yv = yl[ti][0][p] + yl[ti][1][p] + yl[ti][2][p] + yl[ti][3][p];
      yv += Dh * xs[bl*DI + h*HD + p];
      y[bl*DI + h*HD + p] = yv;
    }
    __syncthreads();
  }
}

// ---------------- gating + RMSNorm -> bf16 ----------------
__global__ __launch_bounds__(256)
void k_gate_norm(const float* __restrict__ y, const float* __restrict__ zx,
                 const float* __restrict__ nw, bf16* __restrict__ yn)
{
  const size_t bl = blockIdx.x;
  const int tid = threadIdx.x;
  float v[8];
  float acc = 0.f;
  #pragma unroll
  for (int i = 0; i < 8; ++i) {
    const int cch = tid + i*256;
    float yv = y[bl*DI + cch];
    const float zv = zx[bl*DPAD + cch];
    const float g = zv / (1.f + __expf(-zv));
    yv *= g;
    v[i] = yv;
    acc += yv*yv;
  }
  #pragma unroll
  for (int off = 32; off > 0; off >>= 1) acc += __shfl_down(acc, off);
  __shared__ float red[4];
  if ((tid & 63) == 0) red[tid >> 6] = acc;
  __syncthreads();
  const float total = red[0] + red[1] + red[2] + red[3];
  const float r = rsqrtf(total * (1.f/DI) + 1e-5f);
  #pragma unroll
  for (int i = 0; i < 8; ++i) {
    const int cch = tid + i*256;
    yn[bl*DI + cch] = f2bf(v[i] * r * nw[cch]);
  }
}

// ---------------- launch ----------------
extern "C" void kernel_launch(void* const* d_in, const int* in_sizes, int n_in,
                              void* d_out, int out_size, void* d_ws, size_t ws_size,
                              hipStream_t stream)
{
  const float* x     = (const float*)d_in[0];
  const float* inw   = (const float*)d_in[1];
  const float* convw = (const float*)d_in[2];
  const float* convb = (const float*)d_in[3];
  const float* dtb   = (const float*)d_in[4];
  const float* alog  = (const float*)d_in[5];
  const float* Dv    = (const float*)d_in[6];
  const float* nw    = (const float*)d_in[7];
  const float* outw  = (const float*)d_in[8];
  float* out = (float*)d_out;
  char* ws = (char*)d_ws;

  constexpr size_t OFF_ZX   = 0;                                       // f32 [4096][4480]
  constexpr size_t OFF_XS   = OFF_ZX   + (size_t)NBL*DPAD*4;           // f32 [4096][2048]
  constexpr size_t OFF_DT   = OFF_XS   + (size_t)NBL*DI*4;             // f32 [4096][32]
  constexpr size_t OFF_LDA  = OFF_DT   + (size_t)NBL*NH*4;             // f32 [4096][32]
  constexpr size_t OFF_B    = OFF_LDA  + (size_t)NBL*NH*4;             // f32 [4096][128]
  constexpr size_t OFF_C    = OFF_B    + (size_t)NBL*DS*4;             // f32 [4096][128]
  constexpr size_t OFF_SLOC = OFF_C    + (size_t)NBL*DS*4;             // f32 [1024][8192]
  constexpr size_t OFF_CLOG = OFF_SLOC + (size_t)1024*8192*4;          // f32 [1024]
  constexpr size_t OFF_Y    = OFF_CLOG + 4096;                         // f32 [4096][2048]
  constexpr size_t OFF_YN   = OFF_Y    + (size_t)NBL*DI*4;             // bf16 [4096][2048]
  constexpr size_t OFF_XB   = OFF_YN   + (size_t)NBL*DI*2;             // bf16 [4096][1024]
  constexpr size_t OFF_INWB = OFF_XB   + (size_t)NBL*DM*2;             // bf16 [4384][1024]
  constexpr size_t OFF_OUTWB= OFF_INWB + (size_t)DPROJ*DM*2;           // bf16 [1024][2048]

  float* zx   = (float*)(ws + OFF_ZX);
  float* xs   = (float*)(ws + OFF_XS);
  float* dt   = (float*)(ws + OFF_DT);
  float* ldA  = (float*)(ws + OFF_LDA);
  float* Bc   = (float*)(ws + OFF_B);
  float* Cc   = (float*)(ws + OFF_C);
  float* Sloc = (float*)(ws + OFF_SLOC);
  float* clog = (float*)(ws + OFF_CLOG);
  float* yb   = (float*)(ws + OFF_Y);
  bf16*  yn   = (bf16*) (ws + OFF_YN);
  bf16*  xb   = (bf16*) (ws + OFF_XB);
  bf16*  inwb = (bf16*) (ws + OFF_INWB);
  bf16*  outwb= (bf16*) (ws + OFF_OUTWB);

  // 0) cast f32 inputs to bf16 for the MFMA GEMMs
  k_cast<<<1024, 256, 0, stream>>>(x,    xb,    NBL*DM/4);
  k_cast<<<1024, 256, 0, stream>>>(inw,  inwb,  DPROJ*DM/4);
  k_cast<<<1024, 256, 0, stream>>>(outw, outwb, DM*DI/4);
  // 1) zxbcdt = x @ in_proj_w^T  (f32 out, padded ld 4480)
  k_gemm_nt<false><<<dim3(32, 35), 256, 0, stream>>>(xb, inwb, DM, DPROJ, DPAD, zx, nullptr);
  // 2) conv + silu + dt/ldA
  k_conv<<<NBL, 256, 0, stream>>>(zx, convw, convb, dtb, alog, xs, dt, ldA, Bc, Cc);
  // 3) chunked scan
  k_chunk_state<<<BB*NH*NCHK, 256, 0, stream>>>(xs, dt, ldA, Bc, Sloc, clog);
  k_chunk_combine<<<64*8, 256, 0, stream>>>(Sloc, clog);
  k_chunk_scan<<<BB*NH*NCHK, 256, 0, stream>>>(xs, dt, ldA, Bc, Cc, Sloc, Dv, yb);
  // 4) gating + RMSNorm
  k_gate_norm<<<NBL, 256, 0, stream>>>(yb, zx, nw, yn);
  // 5) out = x + yn @ out_proj_w^T (f32 residual add)
  k_gemm_nt<true><<<dim3(32, 8), 256, 0, stream>>>(yn, outwb, DI, DM, DM, out, x);
}

// Round 3
// 256.243 us; speedup vs baseline: 1.9672x; 1.9672x over previous
//
#include <hip/hip_runtime.h>
#include <hip/hip_bf16.h>
#include <cstdint>

typedef __hip_bfloat16 bf16;
typedef __attribute__((ext_vector_type(8))) short short8;
typedef __attribute__((ext_vector_type(4))) float f32x4;
typedef unsigned int u32;

#define BB 2
#define LL 2048
#define DM 1024
#define DI 2048
#define DS 128
#define NH 32
#define HD 64
#define CONVD 2304
#define DPROJ 4384
#define DPAD 4480
#define NBL (BB*LL)
#define NCHK 16
#define CLEN 128

__device__ __forceinline__ float bf2f(bf16 v) { return __bfloat162float(v); }
__device__ __forceinline__ bf16 f2bf(float f) { return __float2bfloat16(f); }
__device__ __forceinline__ unsigned short f2bfu(float f) {
  bf16 t = __float2bfloat16(f); return *(unsigned short*)&t;
}
__device__ __forceinline__ float bfu2f(unsigned short u) {
  u32 b = ((u32)u) << 16; return *(float*)&b;
}

__device__ __forceinline__ void gload16(const void* g, void* l) {
  __builtin_amdgcn_global_load_lds(
      (const __attribute__((address_space(1))) u32*)g,
      (__attribute__((address_space(3))) u32*)l, 16, 0, 0);
}

// ---------------- f32 -> bf16 cast (vectorized) ----------------
__global__ __launch_bounds__(256)
void k_cast(const float* __restrict__ src, bf16* __restrict__ dst, int n4)
{
  int i = blockIdx.x * blockDim.x + threadIdx.x;
  const int stride = gridDim.x * blockDim.x;
  for (; i < n4; i += stride) {
    const float4 v = ((const float4*)src)[i];
    u32 w0 = (u32)f2bfu(v.x) | ((u32)f2bfu(v.y) << 16);
    u32 w1 = (u32)f2bfu(v.z) | ((u32)f2bfu(v.w) << 16);
    *(uint2*)(dst + (size_t)i*4) = make_uint2(w0, w1);
  }
}

// ---------------- GEMM (NT): out[m][n] = sum_k A[m][k] * W[n][k] ----------------
template<bool ADDRES>
__global__ __launch_bounds__(256)
void k_gemm_nt(const bf16* __restrict__ A, const bf16* __restrict__ W,
               int K, int Nw, int ldo,
               float* __restrict__ outf, const float* __restrict__ resid)
{
  __shared__ __align__(16) unsigned short As[128*64];
  __shared__ __align__(16) unsigned short Ws[128*64];
  const int tid = threadIdx.x;
  const int w = tid >> 6, lane = tid & 63;
  const int m0 = blockIdx.x * 128, n0 = blockIdx.y * 128;
  const int wr = w >> 1, wc = w & 1;
  f32x4 acc[4][4] = {};
  const int r0 = lane & 15;
  const int kq = (lane >> 4) * 8;

  for (int k0 = 0; k0 < K; k0 += 64) {
    #pragma unroll
    for (int it = 0; it < 4; ++it) {
      const int seg = w*4 + it;
      const int idx = seg*512 + lane*8;
      const int row = idx >> 6, col = idx & 63;
      const bf16* ga = A + (size_t)(m0 + row)*K + (k0 + col);
      gload16(ga, (char*)As + seg*1024);
      int rw = n0 + row; rw = (rw < Nw) ? rw : (Nw - 1);
      const bf16* gw = W + (size_t)rw*K + (k0 + col);
      gload16(gw, (char*)Ws + seg*1024);
    }
    __syncthreads();
    #pragma unroll
    for (int kk = 0; kk < 64; kk += 32) {
      short8 af[4], bw[4];
      #pragma unroll
      for (int mi = 0; mi < 4; ++mi)
        af[mi] = *(const short8*)(As + (wr*64 + mi*16 + r0)*64 + kk + kq);
      #pragma unroll
      for (int ni = 0; ni < 4; ++ni)
        bw[ni] = *(const short8*)(Ws + (wc*64 + ni*16 + r0)*64 + kk + kq);
      #pragma unroll
      for (int mi = 0; mi < 4; ++mi)
        #pragma unroll
        for (int ni = 0; ni < 4; ++ni)
          acc[mi][ni] = __builtin_amdgcn_mfma_f32_16x16x32_bf16(af[mi], bw[ni], acc[mi][ni], 0, 0, 0);
    }
    __syncthreads();
  }
  const int rr = (lane >> 4) * 4;
  #pragma unroll
  for (int mi = 0; mi < 4; ++mi) {
    #pragma unroll
    for (int ni = 0; ni < 4; ++ni) {
      const int col = n0 + wc*64 + ni*16 + r0;
      #pragma unroll
      for (int r = 0; r < 4; ++r) {
        const int row = m0 + wr*64 + mi*16 + rr + r;
        float v = acc[mi][ni][r];
        if (ADDRES) v += resid[(size_t)row*ldo + col];
        outf[(size_t)row*ldo + col] = v;
      }
    }
  }
}

// ---------------- conv1d + silu + dt/ldA prep (bf16 outputs for scan) ----------------
__global__ __launch_bounds__(256)
void k_conv(const float* __restrict__ zx, const float* __restrict__ convw,
            const float* __restrict__ convb, const float* __restrict__ dtb,
            const float* __restrict__ alog,
            bf16* __restrict__ xs, float* __restrict__ dt,
            float* __restrict__ ldA, bf16* __restrict__ Bc, bf16* __restrict__ Cc)
{
  const int bl = blockIdx.x;
  const int l = bl & (LL - 1);
  const int tid = threadIdx.x;
  if (tid < NH) {
    float raw = zx[(size_t)bl*DPAD + (DI + CONVD) + tid] + dtb[tid];
    float sp = (raw > 20.f) ? raw : log1pf(__expf(raw));
    float Ah = -__expf(alog[tid]);
    dt[(size_t)bl*NH + tid] = sp;
    ldA[(size_t)bl*NH + tid] = sp * Ah;
  }
  #pragma unroll
  for (int i = 0; i < 9; ++i) {
    const int c = tid + i*256;
    float acc = convb[c];
    #pragma unroll
    for (int k = 0; k < 4; ++k) {
      const int tt = l - 3 + k;
      if (tt >= 0) acc += zx[(size_t)(bl - 3 + k)*DPAD + DI + c] * convw[c*4 + k];
    }
    const float v = acc / (1.f + __expf(-acc));
    if (c < DI)            xs[(size_t)bl*DI + c] = f2bf(v);
    else if (c < DI + DS)  Bc[(size_t)bl*DS + (c - DI)] = f2bf(v);
    else                   Cc[(size_t)bl*DS + (c - DI - DS)] = f2bf(v);
  }
}

// ---------------- transpose B per (b,chunk): BT[n][t] = B[t][n] ----------------
__global__ __launch_bounds__(256)
void k_bt(const bf16* __restrict__ Bc, bf16* __restrict__ BT)
{
  const int bidx2 = blockIdx.x;               // b*16 + c
  const int b = bidx2 >> 4, c = bidx2 & 15;
  const int bl0 = b*LL + c*CLEN;
  __shared__ unsigned short LT[128*132];
  const int tid = threadIdx.x;
  {
    const int ts = tid >> 3, seg = tid & 7;
    #pragma unroll
    for (int r = 0; r < 4; ++r) {
      const int t = r*32 + ts;
      const unsigned short* src = (const unsigned short*)(Bc + (size_t)(bl0 + t)*DS);
      short8 v0 = *(const short8*)(src + seg*16);
      short8 v1 = *(const short8*)(src + seg*16 + 8);
      u32 w0 = (u32)(unsigned short)v0[0] | ((u32)(unsigned short)v0[1] << 16);
      u32 w1 = (u32)(unsigned short)v0[2] | ((u32)(unsigned short)v0[3] << 16);
      u32 w2 = (u32)(unsigned short)v0[4] | ((u32)(unsigned short)v0[5] << 16);
      u32 w3 = (u32)(unsigned short)v0[6] | ((u32)(unsigned short)v0[7] << 16);
      u32 w4 = (u32)(unsigned short)v1[0] | ((u32)(unsigned short)v1[1] << 16);
      u32 w5 = (u32)(unsigned short)v1[2] | ((u32)(unsigned short)v1[3] << 16);
      u32 w6 = (u32)(unsigned short)v1[4] | ((u32)(unsigned short)v1[5] << 16);
      u32 w7 = (u32)(unsigned short)v1[6] | ((u32)(unsigned short)v1[7] << 16);
      uint2* d = (uint2*)&LT[t*132 + seg*16];
      d[0] = make_uint2(w0, w1); d[1] = make_uint2(w2, w3);
      d[2] = make_uint2(w4, w5); d[3] = make_uint2(w6, w7);
    }
  }
  __syncthreads();
  {
    const int n = tid >> 1, th = tid & 1;
    unsigned short* dst = (unsigned short*)(BT + (size_t)bidx2*16384 + n*128 + th*64);
    #pragma unroll
    for (int j = 0; j < 8; ++j) {
      short8 o;
      #pragma unroll
      for (int e = 0; e < 8; ++e)
        o[e] = (short)LT[(th*64 + j*8 + e)*132 + n];
      *(short8*)(dst + j*8) = o;
    }
  }
}

// ---------------- transpose x per (b,h,chunk): xT[p][t] = x[t][p] * dt[t] ----------------
__global__ __launch_bounds__(256)
void k_xt(const bf16* __restrict__ xs, const float* __restrict__ dt,
          bf16* __restrict__ xT)
{
  const int bidx = blockIdx.x;
  const int c = bidx & 15, h = (bidx >> 4) & 31, b = bidx >> 9;
  const int bl0 = b*LL + c*CLEN;
  __shared__ unsigned short LT[128*68];
  const int tid = threadIdx.x;
  {
    const int ts = tid >> 3, seg = tid & 7;
    #pragma unroll
    for (int r = 0; r < 4; ++r) {
      const int t = r*32 + ts;
      const float dtv = dt[(size_t)(bl0 + t)*NH + h];
      short8 v = *(const short8*)((const unsigned short*)(xs + (size_t)(bl0 + t)*DI + h*HD) + seg*8);
      unsigned short o[8];
      #pragma unroll
      for (int e = 0; e < 8; ++e)
        o[e] = f2bfu(bfu2f((unsigned short)v[e]) * dtv);
      u32 w0 = (u32)o[0] | ((u32)o[1] << 16);
      u32 w1 = (u32)o[2] | ((u32)o[3] << 16);
      u32 w2 = (u32)o[4] | ((u32)o[5] << 16);
      u32 w3 = (u32)o[6] | ((u32)o[7] << 16);
      uint2* d = (uint2*)&LT[t*68 + seg*8];
      d[0] = make_uint2(w0, w1);
      d[1] = make_uint2(w2, w3);
    }
  }
  __syncthreads();
  {
    const int p = tid >> 2, tb = tid & 3;
    unsigned short* dst = (unsigned short*)(xT + (size_t)bidx*8192 + p*128 + tb*32);
    #pragma unroll
    for (int j = 0; j < 4; ++j) {
      short8 o;
      #pragma unroll
      for (int e = 0; e < 8; ++e)
        o[e] = (short)LT[(tb*32 + j*8 + e)*68 + p];
      *(short8*)(dst + j*8) = o;
    }
  }
}

// ---------------- scan phase A (MFMA): S_loc[p][n] = sum_t xT[p][t]*w1[t]*BT[n][t] ----------------
__global__ __launch_bounds__(512)
void k_state(const bf16* __restrict__ xT, const bf16* __restrict__ BT,
             const float* __restrict__ ldA, float* __restrict__ Sloc,
             float* __restrict__ clog)
{
  const int bidx = blockIdx.x;
  const int c = bidx & 15, h = (bidx >> 4) & 31, b = bidx >> 9;
  const int bl0 = b*LL + c*CLEN;
  const int bidx2 = b*NCHK + c;
  __shared__ __align__(16) unsigned short BTs[128*136];
  __shared__ __align__(16) unsigned short XWs[64*136];
  __shared__ float la[128];
  __shared__ float w1[128];
  const int tid = threadIdx.x;
  if (tid < 128) la[tid] = ldA[(size_t)(bl0 + tid)*NH + h];
  {
    const int n = tid >> 2, sg = tid & 3;
    const unsigned short* src = (const unsigned short*)(BT + (size_t)bidx2*16384 + n*128 + sg*32);
    #pragma unroll
    for (int j = 0; j < 4; ++j)
      *(short8*)&BTs[n*136 + sg*32 + j*8] = *(const short8*)(src + j*8);
  }
  __syncthreads();
  #pragma unroll
  for (int off = 1; off < 128; off <<= 1) {
    float v = 0.f;
    if (tid < 128 && tid >= off) v = la[tid - off];
    __syncthreads();
    if (tid < 128 && tid >= off) la[tid] += v;
    __syncthreads();
  }
  if (tid < 128) w1[tid] = __expf(la[127] - la[tid]);
  if (tid == 0) clog[bidx] = la[127];
  __syncthreads();
  {
    const int p = tid >> 3, seg = tid & 7;
    const unsigned short* src = (const unsigned short*)(xT + (size_t)bidx*8192 + p*128) + seg*16;
    #pragma unroll
    for (int half = 0; half < 2; ++half) {
      short8 v = *(const short8*)(src + half*8);
      short8 o;
      #pragma unroll
      for (int e = 0; e < 8; ++e) {
        const int t = seg*16 + half*8 + e;
        o[e] = (short)f2bfu(bfu2f((unsigned short)v[e]) * w1[t]);
      }
      *(short8*)&XWs[p*136 + seg*16 + half*8] = o;
    }
  }
  __syncthreads();
  const int w = tid >> 6, lane = tid & 63;
  const int r0 = lane & 15, kq = (lane >> 4) * 8;
  f32x4 acc[4] = {};
  #pragma unroll
  for (int kk = 0; kk < 4; ++kk) {
    short8 bfrag = *(const short8*)&BTs[(w*16 + r0)*136 + kk*32 + kq];
    #pragma unroll
    for (int mi = 0; mi < 4; ++mi) {
      short8 a = *(const short8*)&XWs[(mi*16 + r0)*136 + kk*32 + kq];
      acc[mi] = __builtin_amdgcn_mfma_f32_16x16x32_bf16(a, bfrag, acc[mi], 0, 0, 0);
    }
  }
  const int rr = (lane >> 4) * 4;
  float* So = Sloc + (size_t)bidx*8192;
  #pragma unroll
  for (int mi = 0; mi < 4; ++mi)
    #pragma unroll
    for (int r = 0; r < 4; ++r)
      So[(mi*16 + rr + r)*128 + w*16 + r0] = acc[mi][r];
}

// ---------------- scan phase B: inter-chunk recurrence (in-place: Sloc -> Sinit) ----------------
__global__ __launch_bounds__(256)
void k_chunk_combine(float* __restrict__ Sloc, const float* __restrict__ clog)
{
  const int bh = blockIdx.x >> 3;
  const int e0 = ((blockIdx.x & 7) * 256 + threadIdx.x) * 4;
  float4 tmp = {0.f, 0.f, 0.f, 0.f};
  for (int c = 0; c < NCHK; ++c) {
    float* Sp = Sloc + ((size_t)(bh*NCHK + c))*8192 + e0;
    const float4 loc = *(const float4*)Sp;
    *(float4*)Sp = tmp;
    const float P = __expf(clog[bh*NCHK + c]);
    tmp.x = P*tmp.x + loc.x;
    tmp.y = P*tmp.y + loc.y;
    tmp.z = P*tmp.z + loc.z;
    tmp.w = P*tmp.w + loc.w;
  }
}

// ---------------- scan phase C (MFMA): Y = M@XD + diag(exp(la))*(C@Sinit^T) + D*x ----------------
__global__ __launch_bounds__(512)
void k_scan(const bf16* __restrict__ xT, const bf16* __restrict__ Bc,
            const bf16* __restrict__ Cc, const float* __restrict__ Sinit,
            const float* __restrict__ ldA, const bf16* __restrict__ xs,
            const float* __restrict__ Dv, float* __restrict__ y)
{
  const int bidx = blockIdx.x;
  const int c = bidx & 15, h = (bidx >> 4) & 31, b = bidx >> 9;
  const int bl0 = b*LL + c*CLEN;
  __shared__ __align__(16) unsigned short Cs[128*136];
  __shared__ __align__(16) unsigned short Bs[128*136];   // becomes M after G
  __shared__ __align__(16) unsigned short XDs[64*136];
  __shared__ __align__(16) unsigned short SIs[64*136];
  __shared__ float la[128];
  const int tid = threadIdx.x;
  if (tid < 128) la[tid] = ldA[(size_t)(bl0 + tid)*NH + h];
  {
    const int t = tid >> 2, sg = tid & 3;
    const unsigned short* sc = (const unsigned short*)(Cc + (size_t)(bl0 + t)*DS) + sg*32;
    const unsigned short* sb = (const unsigned short*)(Bc + (size_t)(bl0 + t)*DS) + sg*32;
    #pragma unroll
    for (int j = 0; j < 4; ++j) {
      *(short8*)&Cs[t*136 + sg*32 + j*8] = *(const short8*)(sc + j*8);
      *(short8*)&Bs[t*136 + sg*32 + j*8] = *(const short8*)(sb + j*8);
    }
  }
  {
    const int p = tid >> 3, seg = tid & 7;
    const unsigned short* sx = (const unsigned short*)(xT + (size_t)bidx*8192 + p*128) + seg*16;
    *(short8*)&XDs[p*136 + seg*16]     = *(const short8*)sx;
    *(short8*)&XDs[p*136 + seg*16 + 8] = *(const short8*)(sx + 8);
    const float4* sp = (const float4*)(Sinit + (size_t)bidx*8192 + p*128 + seg*16);
    float4 f0 = sp[0], f1 = sp[1], f2 = sp[2], f3 = sp[3];
    short8 o0, o1;
    o0[0] = (short)f2bfu(f0.x); o0[1] = (short)f2bfu(f0.y);
    o0[2] = (short)f2bfu(f0.z); o0[3] = (short)f2bfu(f0.w);
    o0[4] = (short)f2bfu(f1.x); o0[5] = (short)f2bfu(f1.y);
    o0[6] = (short)f2bfu(f1.z); o0[7] = (short)f2bfu(f1.w);
    o1[0] = (short)f2bfu(f2.x); o1[1] = (short)f2bfu(f2.y);
    o1[2] = (short)f2bfu(f2.z); o1[3] = (short)f2bfu(f2.w);
    o1[4] = (short)f2bfu(f3.x); o1[5] = (short)f2bfu(f3.y);
    o1[6] = (short)f2bfu(f3.z); o1[7] = (short)f2bfu(f3.w);
    *(short8*)&SIs[p*136 + seg*16]     = o0;
    *(short8*)&SIs[p*136 + seg*16 + 8] = o1;
  }
  __syncthreads();
  #pragma unroll
  for (int off = 1; off < 128; off <<= 1) {
    float v = 0.f;
    if (tid < 128 && tid >= off) v = la[tid - off];
    __syncthreads();
    if (tid < 128 && tid >= off) la[tid] += v;
    __syncthreads();
  }

  const int w = tid >> 6, lane = tid & 63;
  const int r0 = lane & 15, kq = (lane >> 4) * 8;
  const int trow = w*16 + (lane >> 4) * 4;

  // G = C @ B^T   and   U = C @ Sinit^T   (both contract over n)
  f32x4 aG[8] = {};
  f32x4 aU[4] = {};
  #pragma unroll
  for (int kk = 0; kk < 4; ++kk) {
    short8 a = *(const short8*)&Cs[(w*16 + r0)*136 + kk*32 + kq];
    #pragma unroll
    for (int sf = 0; sf < 8; ++sf) {
      short8 bb = *(const short8*)&Bs[(sf*16 + r0)*136 + kk*32 + kq];
      aG[sf] = __builtin_amdgcn_mfma_f32_16x16x32_bf16(a, bb, aG[sf], 0, 0, 0);
    }
    #pragma unroll
    for (int pf = 0; pf < 4; ++pf) {
      short8 bs = *(const short8*)&SIs[(pf*16 + r0)*136 + kk*32 + kq];
      aU[pf] = __builtin_amdgcn_mfma_f32_16x16x32_bf16(a, bs, aU[pf], 0, 0, 0);
    }
  }
  __syncthreads();      // all waves done reading Bs
  float lat[4];
  #pragma unroll
  for (int r = 0; r < 4; ++r) lat[r] = la[trow + r];
  #pragma unroll
  for (int sf = 0; sf < 8; ++sf) {
    const int s = sf*16 + r0;
    const float las = la[s];
    #pragma unroll
    for (int r = 0; r < 4; ++r) {
      const int t = trow + r;
      const float m = (s <= t) ? aG[sf][r] * __expf(lat[r] - las) : 0.f;
      Bs[t*136 + s] = f2bfu(m);
    }
  }
  __syncthreads();
  // Y = M @ XD^T (contract over s)
  f32x4 aY[4] = {};
  #pragma unroll
  for (int kk = 0; kk < 4; ++kk) {
    short8 a = *(const short8*)&Bs[(w*16 + r0)*136 + kk*32 + kq];
    #pragma unroll
    for (int pf = 0; pf < 4; ++pf) {
      short8 bx = *(const short8*)&XDs[(pf*16 + r0)*136 + kk*32 + kq];
      aY[pf] = __builtin_amdgcn_mfma_f32_16x16x32_bf16(a, bx, aY[pf], 0, 0, 0);
    }
  }
  const float Dh = Dv[h];
  float el[4];
  #pragma unroll
  for (int r = 0; r < 4; ++r) el[r] = __expf(lat[r]);
  #pragma unroll
  for (int pf = 0; pf < 4; ++pf) {
    #pragma unroll
    for (int r = 0; r < 4; ++r) {
      const int t = trow + r, p = pf*16 + r0;
      const size_t gi = (size_t)(bl0 + t)*DI + h*HD + p;
      y[gi] = aY[pf][r] + el[r]*aU[pf][r] + Dh*bfu2f(((const unsigned short*)xs)[gi]);
    }
  }
}

// ---------------- gating + RMSNorm -> bf16 ----------------
__global__ __launch_bounds__(256)
void k_gate_norm(const float* __restrict__ y, const float* __restrict__ zx,
                 const float* __restrict__ nw, bf16* __restrict__ yn)
{
  const size_t bl = blockIdx.x;
  const int tid = threadIdx.x;
  float v[8];
  float acc = 0.f;
  #pragma unroll
  for (int i = 0; i < 8; ++i) {
    const int cch = tid + i*256;
    float yv = y[bl*DI + cch];
    const float zv = zx[bl*DPAD + cch];
    const float g = zv / (1.f + __expf(-zv));
    yv *= g;
    v[i] = yv;
    acc += yv*yv;
  }
  #pragma unroll
  for (int off = 32; off > 0; off >>= 1) acc += __shfl_down(acc, off);
  __shared__ float red[4];
  if ((tid & 63) == 0) red[tid >> 6] = acc;
  __syncthreads();
  const float total = red[0] + red[1] + red[2] + red[3];
  const float r = rsqrtf(total * (1.f/DI) + 1e-5f);
  #pragma unroll
  for (int i = 0; i < 8; ++i) {
    const int cch = tid + i*256;
    yn[bl*DI + cch] = f2bf(v[i] * r * nw[cch]);
  }
}

// ---------------- launch ----------------
extern "C" void kernel_launch(void* const* d_in, const int* in_sizes, int n_in,
                              void* d_out, int out_size, void* d_ws, size_t ws_size,
                              hipStream_t stream)
{
  const float* x     = (const float*)d_in[0];
  const float* inw   = (const float*)d_in[1];
  const float* convw = (const float*)d_in[2];
  const float* convb = (const float*)d_in[3];
  const float* dtb   = (const float*)d_in[4];
  const float* alog  = (const float*)d_in[5];
  const float* Dv    = (const float*)d_in[6];
  const float* nw    = (const float*)d_in[7];
  const float* outw  = (const float*)d_in[8];
  float* out = (float*)d_out;
  char* ws = (char*)d_ws;

  constexpr size_t OFF_ZX   = 0;                                       // f32 [4096][4480]
  constexpr size_t OFF_XS   = OFF_ZX   + (size_t)NBL*DPAD*4;           // bf16 [4096][2048]
  constexpr size_t OFF_DT   = OFF_XS   + (size_t)NBL*DI*2;             // f32 [4096][32]
  constexpr size_t OFF_LDA  = OFF_DT   + (size_t)NBL*NH*4;             // f32 [4096][32]
  constexpr size_t OFF_B    = OFF_LDA  + (size_t)NBL*NH*4;             // bf16 [4096][128]
  constexpr size_t OFF_C    = OFF_B    + (size_t)NBL*DS*2;             // bf16 [4096][128]
  constexpr size_t OFF_XT   = OFF_C    + (size_t)NBL*DS*2;             // bf16 [1024][64][128]
  constexpr size_t OFF_BT   = OFF_XT   + (size_t)1024*8192*2;          // bf16 [32][128][128]
  constexpr size_t OFF_SLOC = OFF_BT   + (size_t)32*16384*2;           // f32 [1024][8192]
  constexpr size_t OFF_CLOG = OFF_SLOC + (size_t)1024*8192*4;          // f32 [1024]
  constexpr size_t OFF_Y    = OFF_CLOG + 4096;                         // f32 [4096][2048]
  constexpr size_t OFF_YN   = OFF_Y    + (size_t)NBL*DI*4;             // bf16 [4096][2048]
  constexpr size_t OFF_XB   = OFF_YN   + (size_t)NBL*DI*2;             // bf16 [4096][1024]
  constexpr size_t OFF_INWB = OFF_XB   + (size_t)NBL*DM*2;             // bf16 [4384][1024]
  constexpr size_t OFF_OUTWB= OFF_INWB + (size_t)DPROJ*DM*2;           // bf16 [1024][2048]

  float* zx   = (float*)(ws + OFF_ZX);
  bf16*  xs   = (bf16*) (ws + OFF_XS);
  float* dt   = (float*)(ws + OFF_DT);
  float* ldA  = (float*)(ws + OFF_LDA);
  bf16*  Bcp  = (bf16*) (ws + OFF_B);
  bf16*  Ccp  = (bf16*) (ws + OFF_C);
  bf16*  xT   = (bf16*) (ws + OFF_XT);
  bf16*  BT   = (bf16*) (ws + OFF_BT);
  float* Sloc = (float*)(ws + OFF_SLOC);
  float* clog = (float*)(ws + OFF_CLOG);
  float* yb   = (float*)(ws + OFF_Y);
  bf16*  yn   = (bf16*) (ws + OFF_YN);
  bf16*  xb   = (bf16*) (ws + OFF_XB);
  bf16*  inwb = (bf16*) (ws + OFF_INWB);
  bf16*  outwb= (bf16*) (ws + OFF_OUTWB);

  // 0) cast f32 inputs to bf16 for the MFMA GEMMs
  k_cast<<<1024, 256, 0, stream>>>(x,    xb,    NBL*DM/4);
  k_cast<<<1024, 256, 0, stream>>>(inw,  inwb,  DPROJ*DM/4);
  k_cast<<<1024, 256, 0, stream>>>(outw, outwb, DM*DI/4);
  // 1) zxbcdt = x @ in_proj_w^T  (f32 out, padded ld 4480)
  k_gemm_nt<false><<<dim3(32, 35), 256, 0, stream>>>(xb, inwb, DM, DPROJ, DPAD, zx, nullptr);
  // 2) conv + silu + dt/ldA  (bf16 xs/B/C)
  k_conv<<<NBL, 256, 0, stream>>>(zx, convw, convb, dtb, alog, xs, dt, ldA, Bcp, Ccp);
  // 3) transposes for the MFMA scan
  k_bt<<<BB*NCHK, 256, 0, stream>>>(Bcp, BT);
  k_xt<<<BB*NH*NCHK, 256, 0, stream>>>(xs, dt, xT);
  // 4) chunked scan (MFMA)
  k_state<<<BB*NH*NCHK, 512, 0, stream>>>(xT, BT, ldA, Sloc, clog);
  k_chunk_combine<<<64*8, 256, 0, stream>>>(Sloc, clog);
  k_scan<<<BB*NH*NCHK, 512, 0, stream>>>(xT, Bcp, Ccp, Sloc, ldA, xs, Dv, yb);
  // 5) gating + RMSNorm
  k_gate_norm<<<NBL, 256, 0, stream>>>(yb, zx, nw, yn);
  // 6) out = x + yn @ out_proj_w^T (f32 residual add)
  k_gemm_nt<true><<<dim3(32, 8), 256, 0, stream>>>(yn, outwb, DI, DM, DM, out, x);
}